// Round 1
// baseline (131.322 us; speedup 1.0000x reference)
//
#include <hip/hip_runtime.h>
#include <stdint.h>

#define CCH 32
#define BATCH 512
#define NROW 1024   // 2*BATCH
#define DDIM 768
#define TILE 128
#define NPAIRS 36   // upper-tri tile pairs of 8x8
#define BK 32

typedef unsigned short u16;
typedef __attribute__((ext_vector_type(8))) short short8v;   // 8 bf16 (4 VGPRs)
typedef __attribute__((ext_vector_type(4))) float f32x4;     // MFMA acc

__device__ __forceinline__ u16 f2bf_rne(float x) {
    uint32_t u = __float_as_uint(x);
    u += 0x7FFFu + ((u >> 16) & 1u);
    return (u16)(u >> 16);
}
__device__ __forceinline__ float bf2f(u16 h) {
    return __uint_as_float(((uint32_t)h) << 16);
}

__device__ __forceinline__ void gload_lds16(const u16* g, u16* l) {
    // async global->LDS, 16B per lane; LDS dest = wave-uniform base + lane*16
    __builtin_amdgcn_global_load_lds(
        (const __attribute__((address_space(1))) unsigned int*)(g),
        (__attribute__((address_space(3))) unsigned int*)(l),
        16, 0, 0);
}

__constant__ int PI_[NPAIRS] = {0,0,0,0,0,0,0,0, 1,1,1,1,1,1,1, 2,2,2,2,2,2,
                                3,3,3,3,3, 4,4,4,4, 5,5,5, 6,6, 7};
__constant__ int PJ_[NPAIRS] = {0,1,2,3,4,5,6,7, 1,2,3,4,5,6,7, 2,3,4,5,6,7,
                                3,4,5,6,7, 4,5,6,7, 5,6,7, 6,7, 7};

// ---------------- prep: fp32 -> bf16 (channel-major) + row norms (from bf16) --------
__global__ __launch_bounds__(256) void k_prep(const float* __restrict__ src,
                                              const float* __restrict__ tgt,
                                              u16* __restrict__ bfbuf,
                                              float* __restrict__ sq) {
    int blk = blockIdx.x;            // c*1024 + i
    int c = blk >> 10;
    int i = blk & 1023;
    const float* rowp = (i < BATCH) ? (src + ((size_t)i * CCH + c) * DDIM)
                                    : (tgt + ((size_t)(i - BATCH) * CCH + c) * DDIM);
    int t = threadIdx.x;
    float ss = 0.f;
    if (t < 192) {                   // 192 * float4 = 768
        float4 v = *(reinterpret_cast<const float4*>(rowp) + t);
        u16 h0 = f2bf_rne(v.x), h1 = f2bf_rne(v.y), h2 = f2bf_rne(v.z), h3 = f2bf_rne(v.w);
        float f0 = bf2f(h0), f1 = bf2f(h1), f2 = bf2f(h2), f3 = bf2f(h3);
        ss = f0 * f0 + f1 * f1 + f2 * f2 + f3 * f3;
        ushort4 hv; hv.x = h0; hv.y = h1; hv.z = h2; hv.w = h3;
        *reinterpret_cast<ushort4*>(bfbuf + (size_t)blk * DDIM + (size_t)t * 4) = hv;
    }
    __shared__ float red[256];
    red[t] = ss;
    __syncthreads();
    for (int s = 128; s > 0; s >>= 1) { if (t < s) red[t] += red[t + s]; __syncthreads(); }
    if (t == 0) sq[blk] = red[0];
}

// ---------------- column sums -> partial ||colsum||^2 per (channel, 128-dim chunk) ---
__global__ __launch_bounds__(128) void k_colsum(const u16* __restrict__ bfbuf,
                                                double* __restrict__ ps2) {
    int c = blockIdx.x / 6, ch = blockIdx.x % 6;
    int d = ch * 128 + threadIdx.x;
    const u16* base = bfbuf + (size_t)c * NROW * DDIM + d;
    double s0 = 0.0, s1 = 0.0, s2 = 0.0, s3 = 0.0;
    for (int i = 0; i < NROW; i += 4) {
        s0 += (double)bf2f(base[(size_t)(i + 0) * DDIM]);
        s1 += (double)bf2f(base[(size_t)(i + 1) * DDIM]);
        s2 += (double)bf2f(base[(size_t)(i + 2) * DDIM]);
        s3 += (double)bf2f(base[(size_t)(i + 3) * DDIM]);
    }
    double s = (s0 + s1) + (s2 + s3);
    __shared__ double red[128];
    red[threadIdx.x] = s * s;
    __syncthreads();
    for (int k = 64; k > 0; k >>= 1) {
        if ((int)threadIdx.x < k) red[threadIdx.x] += red[threadIdx.x + k];
        __syncthreads();
    }
    if (threadIdx.x == 0) ps2[blockIdx.x] = red[0];
}

// ---------------- bandwidth per channel: sum(d2) = 2n*sum(sq) - 2*||colsum||^2 -------
__global__ __launch_bounds__(256) void k_bw(const float* __restrict__ sq,
                                            const double* __restrict__ ps2,
                                            float* __restrict__ bwc) {
    int c = blockIdx.x, t = threadIdx.x;
    const float* sqc = sq + (size_t)c * NROW;
    float s = sqc[t] + sqc[t + 256] + sqc[t + 512] + sqc[t + 768];
    __shared__ float red[256];
    red[t] = s;
    __syncthreads();
    for (int k = 128; k > 0; k >>= 1) { if (t < k) red[t] += red[t + k]; __syncthreads(); }
    if (t == 0) {
        double s2 = 0.0;
        for (int k = 0; k < 6; ++k) s2 += ps2[c * 6 + k];
        double sumd2 = 2.0 * (double)NROW * (double)red[0] - 2.0 * s2;
        double bw = sumd2 / ((double)NROW * (double)NROW - (double)NROW) / 4.0; // /2^(5//2)
        bwc[c] = (float)(-1.0 / (16.0 * bw));  // arg scale for largest bandwidth
    }
}

// ---------------- main: fused GEMM(T*T^T) + RBF-kernel-sum per 128x128 tile pair -----
__global__ __launch_bounds__(256) void k_mmd(const u16* __restrict__ bfbuf,
                                             const float* __restrict__ sq,
                                             const float* __restrict__ bwc,
                                             float* __restrict__ partial) {
    int blk = blockIdx.x;
    int c = blk / NPAIRS, p = blk - c * NPAIRS;
    int ti = PI_[p], tj = PJ_[p];
    const u16* Ab = bfbuf + ((size_t)c * NROW + (size_t)ti * TILE) * DDIM;
    const u16* Bb = bfbuf + ((size_t)c * NROW + (size_t)tj * TILE) * DDIM;

    __shared__ __align__(16) u16 lA[TILE * BK];   // [128][32] bf16, 8 KB
    __shared__ __align__(16) u16 lB[TILE * BK];

    int t = threadIdx.x;
    int wid = t >> 6, lane = t & 63;
    int lr = lane & 15, kg = lane >> 4;
    int wr = wid >> 1, wc = wid & 1;              // 2x2 wave grid; wave owns 64x64

    f32x4 acc[4][4];
#pragma unroll
    for (int m = 0; m < 4; ++m)
#pragma unroll
        for (int n = 0; n < 4; ++n) acc[m][n] = f32x4{0.f, 0.f, 0.f, 0.f};

    for (int k0 = 0; k0 < DDIM; k0 += BK) {
        // stage A,B tiles (128x32 bf16 = 8KB each): 2 issues x 256 lanes x 16B
#pragma unroll
        for (int iss = 0; iss < 2; ++iss) {
            int g = t + iss * 256;                // granule: row = g>>2, 16B-chunk = g&3
            int row = g >> 2;
            int co = (g & 3) * 8;
            const u16* ga = Ab + (size_t)row * DDIM + k0 + co;
            const u16* gb = Bb + (size_t)row * DDIM + k0 + co;
            u16* la = lA + (size_t)(wid * 64 + iss * 256) * 8;  // wave-uniform base
            u16* lb = lB + (size_t)(wid * 64 + iss * 256) * 8;
            gload_lds16(ga, la);
            gload_lds16(gb, lb);
        }
        __syncthreads();

        short8v af[4], bf[4];
#pragma unroll
        for (int m = 0; m < 4; ++m)
            af[m] = *reinterpret_cast<const short8v*>(&lA[(wr * 64 + m * 16 + lr) * BK + kg * 8]);
#pragma unroll
        for (int n = 0; n < 4; ++n)
            bf[n] = *reinterpret_cast<const short8v*>(&lB[(wc * 64 + n * 16 + lr) * BK + kg * 8]);
#pragma unroll
        for (int m = 0; m < 4; ++m)
#pragma unroll
            for (int n = 0; n < 4; ++n)
                acc[m][n] = __builtin_amdgcn_mfma_f32_16x16x32_bf16(af[m], bf[n], acc[m][n], 0, 0, 0);
        __syncthreads();
    }

    // epilogue: d2 -> sum_k exp(-d2/bw_k) via t + t^2 + t^4 + t^8 + t^16
    float ci = bwc[c];                            // -1/(16*bw)
    const float* sqc = sq + (size_t)c * NROW;
    float sqi[4][4], sqj[4];
#pragma unroll
    for (int m = 0; m < 4; ++m)
#pragma unroll
        for (int r = 0; r < 4; ++r)
            sqi[m][r] = sqc[ti * TILE + wr * 64 + m * 16 + kg * 4 + r];
#pragma unroll
    for (int n = 0; n < 4; ++n)
        sqj[n] = sqc[tj * TILE + wc * 64 + n * 16 + lr];

    float psum = 0.f;
#pragma unroll
    for (int m = 0; m < 4; ++m)
#pragma unroll
        for (int n = 0; n < 4; ++n) {
#pragma unroll
            for (int r = 0; r < 4; ++r) {
                // C/D layout (m89-verified): col = lane&15, row = (lane>>4)*4 + r
                float d2 = sqi[m][r] + sqj[n] - 2.0f * acc[m][n][r];
                float t1 = __expf(d2 * ci);
                float t2 = t1 * t1, t4 = t2 * t2, t8 = t4 * t4, t16 = t8 * t8;
                psum += ((t1 + t2) + (t4 + t8)) + t16;
            }
        }

    float* red = reinterpret_cast<float*>(lA);
    red[t] = psum;
    __syncthreads();
    for (int s = 128; s > 0; s >>= 1) { if (t < s) red[t] += red[t + s]; __syncthreads(); }
    if (t == 0) partial[blk] = red[0];
}

// ---------------- final: deterministic combine of 32x36 tile sums --------------------
__global__ __launch_bounds__(64) void k_final(const float* __restrict__ partial,
                                              float* __restrict__ out) {
    int lane = threadIdx.x;
    double r = 0.0;
    if (lane < CCH) {
        const float* pp = partial + (size_t)lane * NPAIRS;
        double s = 0.0;
        for (int q = 0; q < NPAIRS; ++q) {
            int ti = PI_[q], tj = PJ_[q];
            double w = (ti == tj) ? 1.0 : 2.0;               // off-diag pair counted twice
            double sgn = ((ti < 4) == (tj < 4)) ? 1.0 : -1.0; // XX/YY : +, cross : -
            s += sgn * w * (double)pp[q];
        }
        r = s / ((double)BATCH * (double)BATCH);
    }
    for (int off = 16; off > 0; off >>= 1) r += __shfl_down(r, off);
    if (lane == 0) out[0] = (float)(r / (double)CCH);
}

extern "C" void kernel_launch(void* const* d_in, const int* in_sizes, int n_in,
                              void* d_out, int out_size, void* d_ws, size_t ws_size,
                              hipStream_t stream) {
    const float* src = (const float*)d_in[0];
    const float* tgt = (const float*)d_in[1];
    float* out = (float*)d_out;
    char* ws = (char*)d_ws;

    const size_t OFF_BF   = 0;                                       // 50,331,648 B
    const size_t OFF_SQ   = (size_t)CCH * NROW * DDIM * 2;           // +131,072 B
    const size_t OFF_PS2  = OFF_SQ + (size_t)CCH * NROW * 4;         // +1,536 B
    const size_t OFF_BWC  = OFF_PS2 + (size_t)CCH * 6 * 8;           // +128 B
    const size_t OFF_PART = OFF_BWC + (size_t)CCH * 4;               // +4,608 B

    u16*    bfbuf   = (u16*)(ws + OFF_BF);
    float*  sq      = (float*)(ws + OFF_SQ);
    double* ps2     = (double*)(ws + OFF_PS2);
    float*  bwc     = (float*)(ws + OFF_BWC);
    float*  partial = (float*)(ws + OFF_PART);

    k_prep<<<CCH * NROW, 256, 0, stream>>>(src, tgt, bfbuf, sq);
    k_colsum<<<CCH * 6, 128, 0, stream>>>(bfbuf, ps2);
    k_bw<<<CCH, 256, 0, stream>>>(sq, ps2, bwc);
    k_mmd<<<CCH * NPAIRS, 256, 0, stream>>>(bfbuf, sq, bwc, partial);
    k_final<<<1, 64, 0, stream>>>(partial, out);
}

// Round 2
// 100.473 us; speedup vs baseline: 1.3070x; 1.3070x over previous
//
#include <hip/hip_runtime.h>
#include <stdint.h>

#define CCH 32
#define BATCH 512
#define NROW 1024   // 2*BATCH
#define DDIM 768
#define TILE 128
#define NPAIRS 36   // upper-tri tile pairs of 8x8
#define BK 32
#define NSTEP (DDIM / BK)   // 24

typedef unsigned short u16;
typedef __attribute__((ext_vector_type(8))) short short8v;   // 8 bf16 (4 VGPRs)
typedef __attribute__((ext_vector_type(4))) float f32x4;     // MFMA acc

__device__ __forceinline__ u16 f2bf_rne(float x) {
    uint32_t u = __float_as_uint(x);
    u += 0x7FFFu + ((u >> 16) & 1u);
    return (u16)(u >> 16);
}
__device__ __forceinline__ float bf2f(u16 h) {
    return __uint_as_float(((uint32_t)h) << 16);
}

__device__ __forceinline__ void gload_lds16(const u16* g, u16* l) {
    // async global->LDS, 16B per lane; LDS dest = wave-uniform base + lane*16
    __builtin_amdgcn_global_load_lds(
        (const __attribute__((address_space(1))) unsigned int*)(g),
        (__attribute__((address_space(3))) unsigned int*)(l),
        16, 0, 0);
}

__constant__ int PI_[NPAIRS] = {0,0,0,0,0,0,0,0, 1,1,1,1,1,1,1, 2,2,2,2,2,2,
                                3,3,3,3,3, 4,4,4,4, 5,5,5, 6,6, 7};
__constant__ int PJ_[NPAIRS] = {0,1,2,3,4,5,6,7, 1,2,3,4,5,6,7, 2,3,4,5,6,7,
                                3,4,5,6,7, 4,5,6,7, 5,6,7, 6,7, 7};

// ---------------- prep: fp32 -> bf16 (channel-major) + row norms (from bf16) --------
// wave-per-row: 64 lanes x 3 float4 = 768 floats; shuffle reduce; no LDS barriers.
__global__ __launch_bounds__(256) void k_prep(const float* __restrict__ src,
                                              const float* __restrict__ tgt,
                                              u16* __restrict__ bfbuf,
                                              float* __restrict__ sq) {
    int wid = threadIdx.x >> 6, lane = threadIdx.x & 63;
    int row = blockIdx.x * 4 + wid;      // [0, 32768): c*1024 + i
    int c = row >> 10, i = row & 1023;
    const float* rowp = (i < BATCH) ? (src + ((size_t)i * CCH + c) * DDIM)
                                    : (tgt + ((size_t)(i - BATCH) * CCH + c) * DDIM);
    u16* orow = bfbuf + (size_t)row * DDIM;
    float ss = 0.f;
#pragma unroll
    for (int j = 0; j < 3; ++j) {
        float4 v = *(reinterpret_cast<const float4*>(rowp) + lane + j * 64);
        u16 h0 = f2bf_rne(v.x), h1 = f2bf_rne(v.y), h2 = f2bf_rne(v.z), h3 = f2bf_rne(v.w);
        float f0 = bf2f(h0), f1 = bf2f(h1), f2 = bf2f(h2), f3 = bf2f(h3);
        ss += f0 * f0 + f1 * f1 + f2 * f2 + f3 * f3;
        ushort4 hv; hv.x = h0; hv.y = h1; hv.z = h2; hv.w = h3;
        *reinterpret_cast<ushort4*>(orow + (size_t)(lane + j * 64) * 4) = hv;
    }
#pragma unroll
    for (int off = 32; off > 0; off >>= 1) ss += __shfl_down(ss, off);
    if (lane == 0) sq[row] = ss;
}

// ---------------- partial column sums over 128-row chunks -----------------------------
// grid 32*8 = 256 blocks; colpart[c][ic][d] f32
__global__ __launch_bounds__(256) void k_colsum(const u16* __restrict__ bfbuf,
                                                float* __restrict__ colpart) {
    int c = blockIdx.x >> 3, ic = blockIdx.x & 7;
    const u16* base = bfbuf + ((size_t)c * NROW + (size_t)ic * 128) * DDIM;
#pragma unroll
    for (int j = 0; j < 3; ++j) {
        int d = threadIdx.x + j * 256;
        float s0 = 0.f, s1 = 0.f;
        for (int r = 0; r < 128; r += 2) {
            s0 += bf2f(base[(size_t)r * DDIM + d]);
            s1 += bf2f(base[(size_t)(r + 1) * DDIM + d]);
        }
        colpart[((size_t)c * 8 + ic) * DDIM + d] = s0 + s1;
    }
}

// ---------------- bandwidth: sum(d2) = 2n*sum(sq) - 2*||colsum||^2 --------------------
__global__ __launch_bounds__(256) void k_bw(const float* __restrict__ sq,
                                            const float* __restrict__ colpart,
                                            float* __restrict__ bwc) {
    int c = blockIdx.x, t = threadIdx.x;
    const float* sqc = sq + (size_t)c * NROW;
    float s = sqc[t] + sqc[t + 256] + sqc[t + 512] + sqc[t + 768];
    float s2 = 0.f;
#pragma unroll
    for (int j = 0; j < 3; ++j) {
        int d = t + j * 256;
        float cs = 0.f;
#pragma unroll
        for (int ic = 0; ic < 8; ++ic) cs += colpart[((size_t)c * 8 + ic) * DDIM + d];
        s2 += cs * cs;
    }
    __shared__ float redA[256], redB[256];
    redA[t] = s; redB[t] = s2;
    __syncthreads();
    for (int k = 128; k > 0; k >>= 1) {
        if (t < k) { redA[t] += redA[t + k]; redB[t] += redB[t + k]; }
        __syncthreads();
    }
    if (t == 0) {
        double sumd2 = 2.0 * (double)NROW * (double)redA[0] - 2.0 * (double)redB[0];
        double bw = sumd2 / ((double)NROW * (double)NROW - (double)NROW) / 4.0; // /2^(5//2)
        bwc[c] = (float)(-1.0 / (16.0 * bw));  // arg scale for largest bandwidth
    }
}

// ---------------- main: 2-phase pipelined GEMM + RBF-kernel-sum per tile pair --------
__global__ __launch_bounds__(256) void k_mmd(const u16* __restrict__ bfbuf,
                                             const float* __restrict__ sq,
                                             const float* __restrict__ bwc,
                                             float* __restrict__ partial) {
    // bijective XCD swizzle: 1152 = 8 * 144, 144 blocks (4 channels) per XCD
    int orig = blockIdx.x;
    int blk = (orig & 7) * 144 + (orig >> 3);
    int c = blk / NPAIRS, p = blk - c * NPAIRS;
    int ti = PI_[p], tj = PJ_[p];
    const u16* Ab = bfbuf + ((size_t)c * NROW + (size_t)ti * TILE) * DDIM;
    const u16* Bb = bfbuf + ((size_t)c * NROW + (size_t)tj * TILE) * DDIM;

    __shared__ __align__(16) u16 lA[2][TILE * BK];   // 2 x 8 KB
    __shared__ __align__(16) u16 lB[2][TILE * BK];   // 2 x 8 KB  (32 KB total)

    int t = threadIdx.x;
    int wid = t >> 6, lane = t & 63;
    int lr = lane & 15, kg = lane >> 4;
    int wr = wid >> 1, wc = wid & 1;              // 2x2 wave grid; wave owns 64x64

    // stage one 128x32 A-tile + B-tile into buffer `buf` (4 gload_lds per lane)
    auto STAGE = [&](int buf, int k0) {
#pragma unroll
        for (int iss = 0; iss < 2; ++iss) {
            int g = t + iss * 256;                // granule: row = g>>2, slot = g&3
            int row = g >> 2;
            int kc = ((g & 3) ^ ((row >> 1) & 3)) * 8;   // inverse-swizzled source chunk
            const u16* ga = Ab + (size_t)row * DDIM + k0 + kc;
            const u16* gb = Bb + (size_t)row * DDIM + k0 + kc;
            u16* la = &lA[buf][(size_t)(wid * 64 + iss * 256) * 8];  // wave-uniform base
            u16* lb = &lB[buf][(size_t)(wid * 64 + iss * 256) * 8];
            gload_lds16(ga, la);
            gload_lds16(gb, lb);
        }
    };

    f32x4 acc[4][4];
#pragma unroll
    for (int m = 0; m < 4; ++m)
#pragma unroll
        for (int n = 0; n < 4; ++n) acc[m][n] = f32x4{0.f, 0.f, 0.f, 0.f};

    // swizzled read slot: (base>>1)&3 == 0 for base = {wr,wc}*64 + {m,n}*16, so slot
    // depends only on lr:  slot = kg ^ ((lr>>1)&3)
    int ks = (kg ^ ((lr >> 1) & 3)) * 8;

    STAGE(0, 0);                                  // prologue: 4 loads in flight

    for (int step = 0; step < NSTEP; ++step) {
        int cur = step & 1;
        if (step + 1 < NSTEP) {
            STAGE(cur ^ 1, (step + 1) * BK);      // prefetch next tile (+4 loads)
            asm volatile("s_waitcnt vmcnt(4)" ::: "memory");  // cur's 4 landed; next stays in flight
        } else {
            asm volatile("s_waitcnt vmcnt(0)" ::: "memory");
        }
        __builtin_amdgcn_s_barrier();             // all waves: cur tile present
        asm volatile("" ::: "memory");

        short8v af[4], bf[4];
#pragma unroll
        for (int m = 0; m < 4; ++m)
            af[m] = *reinterpret_cast<const short8v*>(&lA[cur][(wr * 64 + m * 16 + lr) * BK + ks]);
#pragma unroll
        for (int n = 0; n < 4; ++n)
            bf[n] = *reinterpret_cast<const short8v*>(&lB[cur][(wc * 64 + n * 16 + lr) * BK + ks]);
#pragma unroll
        for (int m = 0; m < 4; ++m)
#pragma unroll
            for (int n = 0; n < 4; ++n)
                acc[m][n] = __builtin_amdgcn_mfma_f32_16x16x32_bf16(af[m], bf[n], acc[m][n], 0, 0, 0);

        asm volatile("" ::: "memory");
        __builtin_amdgcn_s_barrier();             // all waves done reading cur -> may overwrite
    }

    // epilogue: d2 -> sum_k exp(-d2/bw_k) via t + t^2 + t^4 + t^8 + t^16
    float ci = bwc[c];                            // -1/(16*bw)
    const float* sqc = sq + (size_t)c * NROW;
    float sqi[4][4], sqj[4];
#pragma unroll
    for (int m = 0; m < 4; ++m)
#pragma unroll
        for (int r = 0; r < 4; ++r)
            sqi[m][r] = sqc[ti * TILE + wr * 64 + m * 16 + kg * 4 + r];
#pragma unroll
    for (int n = 0; n < 4; ++n)
        sqj[n] = sqc[tj * TILE + wc * 64 + n * 16 + lr];

    float psum = 0.f;
#pragma unroll
    for (int m = 0; m < 4; ++m)
#pragma unroll
        for (int n = 0; n < 4; ++n) {
#pragma unroll
            for (int r = 0; r < 4; ++r) {
                // C/D layout (m89-verified): col = lane&15, row = (lane>>4)*4 + r
                float d2 = sqi[m][r] + sqj[n] - 2.0f * acc[m][n][r];
                float t1 = __expf(d2 * ci);
                float t2 = t1 * t1, t4 = t2 * t2, t8 = t4 * t4, t16 = t8 * t8;
                psum += ((t1 + t2) + (t4 + t8)) + t16;
            }
        }

    float* red = reinterpret_cast<float*>(&lA[0][0]);
    red[t] = psum;
    __syncthreads();
    for (int s = 128; s > 0; s >>= 1) { if (t < s) red[t] += red[t + s]; __syncthreads(); }
    if (t == 0) partial[blk] = red[0];
}

// ---------------- final: deterministic combine of 32x36 tile sums --------------------
__global__ __launch_bounds__(64) void k_final(const float* __restrict__ partial,
                                              float* __restrict__ out) {
    int lane = threadIdx.x;
    double r = 0.0;
    if (lane < CCH) {
        const float* pp = partial + (size_t)lane * NPAIRS;
        double s = 0.0;
        for (int q = 0; q < NPAIRS; ++q) {
            int ti = PI_[q], tj = PJ_[q];
            double w = (ti == tj) ? 1.0 : 2.0;               // off-diag pair counted twice
            double sgn = ((ti < 4) == (tj < 4)) ? 1.0 : -1.0; // XX/YY : +, cross : -
            s += sgn * w * (double)pp[q];
        }
        r = s / ((double)BATCH * (double)BATCH);
    }
    for (int off = 16; off > 0; off >>= 1) r += __shfl_down(r, off);
    if (lane == 0) out[0] = (float)(r / (double)CCH);
}

extern "C" void kernel_launch(void* const* d_in, const int* in_sizes, int n_in,
                              void* d_out, int out_size, void* d_ws, size_t ws_size,
                              hipStream_t stream) {
    const float* src = (const float*)d_in[0];
    const float* tgt = (const float*)d_in[1];
    float* out = (float*)d_out;
    char* ws = (char*)d_ws;

    const size_t OFF_BF   = 0;                                       // 50,331,648 B
    const size_t OFF_SQ   = (size_t)CCH * NROW * DDIM * 2;           // +131,072 B
    const size_t OFF_CP   = OFF_SQ + (size_t)CCH * NROW * 4;         // +786,432 B
    const size_t OFF_BWC  = OFF_CP + (size_t)CCH * 8 * DDIM * 4;     // +128 B
    const size_t OFF_PART = OFF_BWC + (size_t)CCH * 4;               // +4,608 B

    u16*   bfbuf   = (u16*)(ws + OFF_BF);
    float* sq      = (float*)(ws + OFF_SQ);
    float* colpart = (float*)(ws + OFF_CP);
    float* bwc     = (float*)(ws + OFF_BWC);
    float* partial = (float*)(ws + OFF_PART);

    k_prep<<<CCH * NROW / 4, 256, 0, stream>>>(src, tgt, bfbuf, sq);
    k_colsum<<<CCH * 8, 256, 0, stream>>>(bfbuf, colpart);
    k_bw<<<CCH, 256, 0, stream>>>(sq, colpart, bwc);
    k_mmd<<<CCH * NPAIRS, 256, 0, stream>>>(bfbuf, sq, bwc, partial);
    k_final<<<1, 64, 0, stream>>>(partial, out);
}